// Round 4
// baseline (2036.342 us; speedup 1.0000x reference)
//
#include <hip/hip_runtime.h>

// LinearRNNwithSoftExp on MI355X (gfx950)  T=1024, B=512, D=128, H=256.
// Round 4: rounds 1-3 all spilled (WRITE_SIZE ~95-110 MB scratch evictions;
// demand ~250 vs 256-reg budget at 2 waves/SIMD). Fix: hoist x-projection to
// a pre-pass GEMM writing XP=fp16(data@ih_w^T+ih_b) into d_ws; recurrent
// kernel drops wih/dh/xacc/x-proj-MFMAs -> ~190 regs, real headroom.
// Recurrent: 256 wgs x 512 thr; wave w owns 32 output cols; whh persistent
// bf16 B-frags (128 regs); h-state bf16 hi+lo in padded LDS ping-pong
// (validated: absmax 6.8e-3, conflicts 0). Fallback to fused r3 kernel if
// ws_size < 256 MiB (branch on call-invariant -> graph-capture safe).

#define TT 1024
#define BB 512
#define DD 128
#define HH 256
#define HP 264   // padded k-row for hbuf (+8 shorts)
#define DP 136   // padded k-row for fallback dbuf
#define XPAD 264 // padded row for xpbuf

typedef __attribute__((ext_vector_type(8))) short bf16x8;
typedef __attribute__((ext_vector_type(4))) float f32x4;

static __device__ __forceinline__ short f2bf(float f) {
    unsigned u = __float_as_uint(f);
    u += 0x7FFFu + ((u >> 16) & 1u);   // round-to-nearest-even
    return (short)(u >> 16);
}
static __device__ __forceinline__ float bf2f(short s) {
    return __uint_as_float(((unsigned)(unsigned short)s) << 16);
}
static __device__ __forceinline__ bf16x8 pack8(const float4 a, const float4 b) {
    bf16x8 v;
    v[0] = f2bf(a.x); v[1] = f2bf(a.y); v[2] = f2bf(a.z); v[3] = f2bf(a.w);
    v[4] = f2bf(b.x); v[5] = f2bf(b.y); v[6] = f2bf(b.z); v[7] = f2bf(b.w);
    return v;
}

// ---------------- pre-pass: XP = fp16(data @ ih_w^T + ih_b) ----------------
// grid 2048 x 256 (4 waves). wg covers m in [256*wg, 256*wg+256) of M=T*B;
// wave w covers n-slice [64w, 64w+64). ih_w B-frags in regs (64), 16 m-tiles.
__global__ __launch_bounds__(256, 1)
void xproj(const float* __restrict__ data, const float* __restrict__ ih_w,
           const float* __restrict__ ih_b, unsigned short* __restrict__ xp)
{
    const int tid  = threadIdx.x;
    const int w    = tid >> 6;
    const int lane = tid & 63;
    const int col  = lane & 15;
    const int quad = lane >> 4;

    bf16x8 wb[4][4];
    #pragma unroll
    for (int j = 0; j < 4; ++j) {
        const float* src = ih_w + (size_t)(64*w + 16*j + col) * DD;
        #pragma unroll
        for (int i = 0; i < 4; ++i) {
            const float4 a = *(const float4*)(src + i*32 + quad*8);
            const float4 b = *(const float4*)(src + i*32 + quad*8 + 4);
            wb[j][i] = pack8(a, b);
        }
    }
    float bias[4];
    #pragma unroll
    for (int j = 0; j < 4; ++j) bias[j] = ih_b[64*w + 16*j + col];

    const size_t mbase = (size_t)blockIdx.x * 256;

    for (int mt = 0; mt < 16; ++mt) {
        const float* arow = data + (mbase + mt*16 + col) * DD;
        bf16x8 afr[4];
        #pragma unroll
        for (int i = 0; i < 4; ++i) {
            const float4 a = *(const float4*)(arow + i*32 + quad*8);
            const float4 b = *(const float4*)(arow + i*32 + quad*8 + 4);
            afr[i] = pack8(a, b);
        }
        f32x4 acc[4];
        #pragma unroll
        for (int j = 0; j < 4; ++j) {
            f32x4 v = {bias[j], bias[j], bias[j], bias[j]}; acc[j] = v;
        }
        #pragma unroll
        for (int i = 0; i < 4; ++i)
            #pragma unroll
            for (int j = 0; j < 4; ++j)
                acc[j] = __builtin_amdgcn_mfma_f32_16x16x32_bf16(
                    afr[i], wb[j][i], acc[j], 0, 0, 0);
        // D layout: col = lane&15 (n), row = quad*4 + r (m within tile)
        #pragma unroll
        for (int j = 0; j < 4; ++j)
            #pragma unroll
            for (int r = 0; r < 4; ++r) {
                const _Float16 h = (_Float16)acc[j][r];
                xp[(mbase + mt*16 + quad*4 + r) * HH + 64*w + 16*j + col] =
                    *(const unsigned short*)&h;
            }
    }
}

// ---------------- recurrent kernel (lean) ----------------
__global__ __launch_bounds__(512, 1)
void rnn_lean(const unsigned short* __restrict__ xp,
              const float* __restrict__ hh_w, const float* __restrict__ hh_b,
              const int* __restrict__ lengths, float* __restrict__ out)
{
    const int g    = blockIdx.x;
    const int tid  = threadIdx.x;
    const int w    = tid >> 6;
    const int lane = tid & 63;
    const int col  = lane & 15;
    const int quad = lane >> 4;

    __shared__ short hbuf[2][2][2][HP];        // [ping][hi/lo][row][k+pad]
    __shared__ unsigned short xpbuf[2][2][XPAD]; // [ping][row][n+pad] fp16 bits

    // whh[s*2+j][i]: s=0 alpha rows 32w+16j, s=1 hbar rows 256+32w+16j
    bf16x8 whh[4][8];
    #pragma unroll
    for (int s = 0; s < 2; ++s)
        #pragma unroll
        for (int j = 0; j < 2; ++j) {
            const float* src = hh_w + (size_t)(s*HH + 32*w + 16*j + col) * HH;
            #pragma unroll
            for (int i = 0; i < 8; ++i) {
                const float4 a = *(const float4*)(src + i*32 + quad*8);
                const float4 b = *(const float4*)(src + i*32 + quad*8 + 4);
                whh[s*2 + j][i] = pack8(a, b);
            }
        }
    float bA[2], bH[2];
    #pragma unroll
    for (int j = 0; j < 2; ++j) {
        bA[j] = hh_b[     32*w + 16*j + col];
        bH[j] = hh_b[HH + 32*w + 16*j + col];
    }

    const int L0 = lengths[2*g];
    const int L1 = lengths[2*g + 1];
    const int Lmax = (L0 > L1) ? L0 : L1;

    const int rr = tid >> 8;        // 0/1: which batch row this thread stages
    const int cc = tid & 255;       // n index staged by this thread

    // prologue: zero h ping 0, stage XP[0]
    for (int idx = tid; idx < 2*2*HP; idx += 512)
        ((short*)hbuf[0])[idx] = 0;
    xpbuf[0][rr][cc] = xp[((size_t)0*BB + 2*g + rr) * HH + cc];
    __syncthreads();

    float  nh[2][2] = {{0.f,0.f},{0.f,0.f}};
    bf16x8 af[4] = {};               // non-act lanes stay 0 forever
    const bool act = (col < 2);      // only A-rows 0,1 are real

    for (int t = 0; t < Lmax; ++t) {
        const int p = t & 1;

        // issue global load of XP[t+1] (consumed next step)
        unsigned short vstage = 0;
        const bool stage = (t + 1 < Lmax);
        if (stage)
            vstage = xp[((size_t)(t+1)*BB + 2*g + rr) * HH + cc];

        // recurrent matmul: hid = h @ hh_w^T + hh_b  (hi then lo pass)
        f32x4 racc[4];
        #pragma unroll
        for (int j = 0; j < 2; ++j) {
            f32x4 va = {bA[j], bA[j], bA[j], bA[j]}; racc[j]     = va;
            f32x4 vh = {bH[j], bH[j], bH[j], bH[j]}; racc[2 + j] = vh;
        }
        #pragma unroll
        for (int part = 0; part < 2; ++part) {          // hi, lo
            #pragma unroll
            for (int half = 0; half < 2; ++half) {      // k-frags 0-3, 4-7
                if (act) {
                    #pragma unroll
                    for (int i = 0; i < 4; ++i)
                        af[i] = *(const bf16x8*)
                            &hbuf[p][part][col][(half*4 + i)*32 + quad*8];
                }
                #pragma unroll
                for (int i = 0; i < 4; ++i)
                    #pragma unroll
                    for (int tt = 0; tt < 4; ++tt)
                        racc[tt] = __builtin_amdgcn_mfma_f32_16x16x32_bf16(
                            af[i], whh[tt][half*4 + i], racc[tt], 0, 0, 0);
            }
        }

        // epilogue: sigmoid, soft-exp gate, tanh, masked update
        // C/D layout: col = lane&15, row = quad*4 + reg; rows 0,1 in quad 0.
        #pragma unroll
        for (int j = 0; j < 2; ++j) {
            #pragma unroll
            for (int r = 0; r < 2; ++r) {
                const float a   = racc[j][r];
                const float hv  = racc[2 + j][r];
                const unsigned short xs = xpbuf[p][r][32*w + 16*j + col];
                const float xv  = (float)(*(const _Float16*)&xs);
                const float e   = __builtin_amdgcn_exp2f(a * -1.4426950408889634f);
                const float inv = 1.0f + e;                    // exactly 1/alpha
                const float al  = __builtin_amdgcn_rcpf(inv);  // alpha
                const float pp  = __builtin_amdgcn_exp2f(al * hv);
                const float gg  = (pp - 1.0f) * inv + al;
                const float u   = xv + gg;
                const float t2  = __builtin_amdgcn_exp2f(u * 2.8853900817779268f);
                const float th  = 1.0f - 2.0f * __builtin_amdgcn_rcpf(1.0f + t2);
                const int   Lr  = r ? L1 : L0;
                const float v   = (t < Lr) ? th : nh[j][r];
                nh[j][r] = v;
                if (quad == 0) {
                    const short hi = f2bf(v);
                    const short lo = f2bf(v - bf2f(hi));
                    hbuf[1 - p][0][r][32*w + 16*j + col] = hi;
                    hbuf[1 - p][1][r][32*w + 16*j + col] = lo;
                }
            }
        }

        // publish staged XP[t+1]
        if (stage)
            xpbuf[1 - p][rr][cc] = vstage;

        __syncthreads();
    }

    if (quad == 0) {
        #pragma unroll
        for (int j = 0; j < 2; ++j)
            #pragma unroll
            for (int r = 0; r < 2; ++r)
                out[(size_t)(2*g + r) * HH + 32*w + 16*j + col] = nh[j][r];
    }
}

// ---------------- fallback: round-3 fused kernel (passes @1913us) ----------
__global__ __launch_bounds__(512, 1)
void rnn_fused_fb(const float* __restrict__ data, const float* __restrict__ ih_w,
                  const float* __restrict__ ih_b, const float* __restrict__ hh_w,
                  const float* __restrict__ hh_b, const int* __restrict__ lengths,
                  float* __restrict__ out)
{
    const int g    = blockIdx.x;
    const int tid  = threadIdx.x;
    const int w    = tid >> 6;
    const int lane = tid & 63;
    const int col  = lane & 15;
    const int quad = lane >> 4;

    __shared__ short hbuf[2][2][2][HP];
    __shared__ short dbuf[2][2][DP];

    bf16x8 whh[4][8];
    #pragma unroll
    for (int s = 0; s < 2; ++s)
        #pragma unroll
        for (int j = 0; j < 2; ++j) {
            const float* src = hh_w + (size_t)(s*HH + 32*w + 16*j + col) * HH;
            #pragma unroll
            for (int i = 0; i < 8; ++i) {
                const float4 a = *(const float4*)(src + i*32 + quad*8);
                const float4 b = *(const float4*)(src + i*32 + quad*8 + 4);
                whh[s*2 + j][i] = pack8(a, b);
            }
        }
    bf16x8 wih[2][4];
    #pragma unroll
    for (int j = 0; j < 2; ++j) {
        const float* src = ih_w + (size_t)(32*w + 16*j + col) * DD;
        #pragma unroll
        for (int i = 0; i < 4; ++i) {
            const float4 a = *(const float4*)(src + i*32 + quad*8);
            const float4 b = *(const float4*)(src + i*32 + quad*8 + 4);
            wih[j][i] = pack8(a, b);
        }
    }
    float bA[2], bH[2], bX[2];
    #pragma unroll
    for (int j = 0; j < 2; ++j) {
        bA[j] = hh_b[     32*w + 16*j + col];
        bH[j] = hh_b[HH + 32*w + 16*j + col];
        bX[j] = ih_b[     32*w + 16*j + col];
    }

    const int L0 = lengths[2*g];
    const int L1 = lengths[2*g + 1];
    const int Lmax = (L0 > L1) ? L0 : L1;

    for (int idx = tid; idx < 2*2*HP; idx += 512)
        ((short*)hbuf[0])[idx] = 0;
    if (tid < 256)
        dbuf[0][tid >> 7][tid & 127] = f2bf(data[(size_t)(2*g) * DD + tid]);
    __syncthreads();

    float  nh[2][2] = {{0.f,0.f},{0.f,0.f}};
    bf16x8 af[4] = {};
    bf16x8 dh[4] = {};
    const bool act = (col < 2);

    for (int t = 0; t < Lmax; ++t) {
        const int p = t & 1;
        float vstage = 0.f;
        const bool stage = (tid < 256) && (t + 1 < Lmax);
        if (stage)
            vstage = data[((size_t)(t+1) * BB + 2*g) * DD + tid];

        f32x4 racc[4];
        #pragma unroll
        for (int j = 0; j < 2; ++j) {
            f32x4 va = {bA[j], bA[j], bA[j], bA[j]}; racc[j]     = va;
            f32x4 vh = {bH[j], bH[j], bH[j], bH[j]}; racc[2 + j] = vh;
        }
        #pragma unroll
        for (int part = 0; part < 2; ++part) {
            #pragma unroll
            for (int half = 0; half < 2; ++half) {
                if (act) {
                    #pragma unroll
                    for (int i = 0; i < 4; ++i)
                        af[i] = *(const bf16x8*)
                            &hbuf[p][part][col][(half*4 + i)*32 + quad*8];
                }
                #pragma unroll
                for (int i = 0; i < 4; ++i)
                    #pragma unroll
                    for (int tt = 0; tt < 4; ++tt)
                        racc[tt] = __builtin_amdgcn_mfma_f32_16x16x32_bf16(
                            af[i], whh[tt][half*4 + i], racc[tt], 0, 0, 0);
            }
        }
        if (act) {
            #pragma unroll
            for (int i = 0; i < 4; ++i)
                dh[i] = *(const bf16x8*)&dbuf[p][col][i*32 + quad*8];
        }
        f32x4 xacc[2];
        #pragma unroll
        for (int j = 0; j < 2; ++j) {
            f32x4 v = {bX[j], bX[j], bX[j], bX[j]}; xacc[j] = v;
        }
        #pragma unroll
        for (int i = 0; i < 4; ++i)
            #pragma unroll
            for (int j = 0; j < 2; ++j)
                xacc[j] = __builtin_amdgcn_mfma_f32_16x16x32_bf16(
                    dh[i], wih[j][i], xacc[j], 0, 0, 0);

        #pragma unroll
        for (int j = 0; j < 2; ++j) {
            #pragma unroll
            for (int r = 0; r < 2; ++r) {
                const float a   = racc[j][r];
                const float hv  = racc[2 + j][r];
                const float e   = __builtin_amdgcn_exp2f(a * -1.4426950408889634f);
                const float inv = 1.0f + e;
                const float al  = __builtin_amdgcn_rcpf(inv);
                const float pp  = __builtin_amdgcn_exp2f(al * hv);
                const float gg  = (pp - 1.0f) * inv + al;
                const float u   = xacc[j][r] + gg;
                const float t2  = __builtin_amdgcn_exp2f(u * 2.8853900817779268f);
                const float th  = 1.0f - 2.0f * __builtin_amdgcn_rcpf(1.0f + t2);
                const int   Lr  = r ? L1 : L0;
                const float v   = (t < Lr) ? th : nh[j][r];
                nh[j][r] = v;
                if (quad == 0) {
                    const short hi = f2bf(v);
                    const short lo = f2bf(v - bf2f(hi));
                    hbuf[1 - p][0][r][32*w + 16*j + col] = hi;
                    hbuf[1 - p][1][r][32*w + 16*j + col] = lo;
                }
            }
        }
        if (stage)
            dbuf[1 - p][tid >> 7][tid & 127] = f2bf(vstage);
        __syncthreads();
    }

    if (quad == 0) {
        #pragma unroll
        for (int j = 0; j < 2; ++j)
            #pragma unroll
            for (int r = 0; r < 2; ++r)
                out[(size_t)(2*g + r) * HH + 32*w + 16*j + col] = nh[j][r];
    }
}

extern "C" void kernel_launch(void* const* d_in, const int* in_sizes, int n_in,
                              void* d_out, int out_size, void* d_ws, size_t ws_size,
                              hipStream_t stream) {
    const float* data    = (const float*)d_in[0];
    const float* ih_w    = (const float*)d_in[1];
    const float* ih_b    = (const float*)d_in[2];
    const float* hh_w    = (const float*)d_in[3];
    const float* hh_b    = (const float*)d_in[4];
    const int*   lengths = (const int*)d_in[5];
    float* out = (float*)d_out;

    (void)in_sizes; (void)n_in; (void)out_size;

    const size_t need = (size_t)TT * BB * HH * sizeof(unsigned short); // 256 MiB
    if (ws_size >= need) {
        unsigned short* xp = (unsigned short*)d_ws;
        xproj<<<dim3((TT * BB) / 256), dim3(256), 0, stream>>>(data, ih_w, ih_b, xp);
        rnn_lean<<<dim3(BB / 2), dim3(512), 0, stream>>>(xp, hh_w, hh_b, lengths, out);
    } else {
        rnn_fused_fb<<<dim3(BB / 2), dim3(512), 0, stream>>>(
            data, ih_w, ih_b, hh_w, hh_b, lengths, out);
    }
}